// Round 12
// baseline (590.732 us; speedup 1.0000x reference)
//
#include <hip/hip_runtime.h>
#include <math.h>

// Problem constants: B=4, C=128, O=128, H=W=128, k=3, K=9, pad=1, stride=1.
#define HWD 16384   // H*W
#define NB  4
#define NC  128
#define NO  128

typedef float  f32x4  __attribute__((ext_vector_type(4)));
typedef short  s16x8  __attribute__((ext_vector_type(8)));

// Split w_reg into bf16 hi/lo, laid out for MFMA A-fragments.
// wA[s][o][kk]: slice s = cc*9 + kt (cc=channel-chunk 0..3, kt=tap 0..8), kk 0..31 -> c = cc*32+kk.
// cc-major so the 9 taps of one channel-chunk run consecutively (L2 row reuse in k_deform).
__global__ void k_split_wreg(const float* __restrict__ w_reg,
                             short* __restrict__ wA_hi, short* __restrict__ wA_lo) {
    int i = blockIdx.x * 256 + threadIdx.x;          // 36*128*32 = 147456
    if (i >= 147456) return;
    int kk = i & 31, o = (i >> 5) & 127, s = i >> 12;
    int cc = s / 9, kt = s % 9;
    int c  = cc * 32 + kk;
    float w = w_reg[o * 1152 + c * 9 + kt];
    unsigned ub = __builtin_bit_cast(unsigned, w);
    unsigned short h = (unsigned short)(ub >> 16);
    float wh = __builtin_bit_cast(float, (unsigned)h << 16);
    float r  = w - wh;
    unsigned short l = (unsigned short)(__builtin_bit_cast(unsigned, r) >> 16);
    wA_hi[i] = (short)h;
    wA_lo[i] = (short)l;
}

// wt_om[(c*9+k)*27 + oc]: oc 0..17 = offset weights, 18..26 = mask weights
__global__ void k_transpose_wom(const float* __restrict__ w_off, const float* __restrict__ w_mod,
                                float* __restrict__ wt_om) {
    int i = blockIdx.x * 256 + threadIdx.x;           // 31104 total
    if (i >= 1152 * 27) return;
    int oc = i % 27, r = i / 27;
    wt_om[i] = (oc < 18) ? w_off[oc * 1152 + r] : w_mod[(oc - 18) * 1152 + r];
}

// 3x3 conv -> 27 raw channels, direct (no LDS staging, no barriers in main loop, no atomics).
// Grid: 256 blocks x 512 threads. Block = 256 px (2 rows); thread t=tid&255 owns 1 px,
// chalf=tid>>8 owns 64 channels; halves reduced via LDS at the end.
__global__ __launch_bounds__(512) void k_conv_om(const float* __restrict__ x,
                                                 const float* __restrict__ wt_om,
                                                 float* __restrict__ cbuf) {
    __shared__ float sred[27 * 256];
    int tid = threadIdx.x;
    int t = tid & 255;
    int chalf = tid >> 8;
    int pxg = blockIdx.x;            // (b, 256-px group)
    int b   = pxg >> 6;
    int hw  = ((pxg & 63) << 8) + t;
    int h = hw >> 7, wcol = hw & 127;

    // per-tap plane offsets + validity masks (channel-invariant)
    int offs[9]; float msk[9];
#pragma unroll
    for (int k = 0; k < 9; ++k) {
        int gy = h + k / 3 - 1, gx = wcol + k % 3 - 1;
        bool vv = (gy >= 0) && (gy < 128) && (gx >= 0) && (gx < 128);
        int cy = min(max(gy, 0), 127), cx = min(max(gx, 0), 127);
        offs[k] = (cy << 7) + cx;
        msk[k]  = vv ? 1.f : 0.f;
    }

    float acc[27];
#pragma unroll
    for (int j = 0; j < 27; ++j) acc[j] = 0.f;

    const float* xb = x + ((size_t)(b * NC + chalf * 64) << 14);
    for (int c = 0; c < 64; ++c) {
        const float* xp = xb + ((size_t)c << 14);
        float v[9];
#pragma unroll
        for (int k = 0; k < 9; ++k) v[k] = xp[offs[k]] * msk[k];
        const float* wp = wt_om + (size_t)(chalf * 64 + c) * 9 * 27;   // uniform -> s_load
#pragma unroll
        for (int k = 0; k < 9; ++k)
#pragma unroll
            for (int j = 0; j < 27; ++j)
                acc[j] = fmaf(wp[k * 27 + j], v[k], acc[j]);
    }

    if (chalf == 1) {
#pragma unroll
        for (int j = 0; j < 27; ++j) sred[j * 256 + t] = acc[j];
    }
    __syncthreads();
    if (chalf == 0) {
#pragma unroll
        for (int j = 0; j < 27; ++j)
            cbuf[((size_t)(b * 27 + j) << 14) + hw] = acc[j] + sred[j * 256 + t];
    }
}

// Deformable gather + bf16-MFMA GEMM (3-pass split precision ~ fp32 accuracy).
// Grid: 1024 blocks x 256 thr (4 waves). XCD-partitioned: xcd=bid&7 owns one (batch, image-half)
// unit (~4.3 MB) so its private L2 holds the working set. Slice s = cc*9+kt (taps inner:
// 9 taps reuse the same 32 channel planes' rows while hot in L1/L2).
// Per slice: MLP-batched gather 32x64 vals -> bf16 hi/lo LDS tile (XOR bank swizzle)
// -> 24 MFMA/wave. 1 barrier/slice, double-buffered.
__global__ __launch_bounds__(256, 4) void k_deform(const float* __restrict__ x,
                                                   const float* __restrict__ cbuf,
                                                   const float* __restrict__ b_off,
                                                   const float* __restrict__ b_mod,
                                                   const short* __restrict__ wA_hi,
                                                   const short* __restrict__ wA_lo,
                                                   float* __restrict__ out) {
    __shared__ int   sp_off[9 * 4 * 64];     // [tap][corner][px] byte offset within channel plane
    __shared__ float sp_w  [9 * 4 * 64];     // premultiplied mask*bilinear*valid
    __shared__ short vt_hi[2][64 * 40];      // [buf][px][kk-chunk XOR-swizzled]
    __shared__ short vt_lo[2][64 * 40];

    int tid = threadIdx.x;
    int bid = blockIdx.x;
    // XCD partition: xcd = bid&7 -> (batch, half); local strip within the half
    int xcd  = bid & 7;
    int b    = xcd >> 1;
    int half = xcd & 1;
    int strip = half * 128 + (bid >> 3);
    int hwbase = strip * 64;
    int lane = tid & 63;
    int wid = tid >> 6;

    // ---- Phase 1: sample descriptors for 64 pixels x 9 taps ----
    for (int i = tid; i < 576; i += 256) {
        int k = i >> 6, p = i & 63;
        int hw = hwbase + p;
        int h = hw >> 7, cc = hw & 127;
        const float* cb = cbuf + ((size_t)(b * 27) << 14);
        float oy = cb[((2 * k) << 14) + hw]     + b_off[2 * k];
        float ox = cb[((2 * k + 1) << 14) + hw] + b_off[2 * k + 1];
        float mr = cb[((18 + k) << 14) + hw]    + b_mod[k];
        float m  = 2.f / (1.f + expf(-mr));
        float py = (float)(h - 1 + k / 3) + oy;
        float px = (float)(cc - 1 + k % 3) + ox;
        float fy = floorf(py), fx = floorf(px);
        float wy1 = py - fy, wx1 = px - fx;
        int y0 = (int)fy, x0 = (int)fx;
#pragma unroll
        for (int dy = 0; dy < 2; ++dy)
#pragma unroll
            for (int dx = 0; dx < 2; ++dx) {
                int yy = y0 + dy, xx = x0 + dx;
                bool valid = (yy >= 0) && (yy < 128) && (xx >= 0) && (xx < 128);
                float wgt = m * (dy ? wy1 : 1.f - wy1) * (dx ? wx1 : 1.f - wx1);
                int yc = min(max(yy, 0), 127), xc = min(max(xx, 0), 127);
                int s = (k * 4 + dy * 2 + dx) * 64 + p;
                sp_off[s] = ((yc << 7) + xc) << 2;
                sp_w[s]   = valid ? wgt : 0.f;
            }
    }
    __syncthreads();

    f32x4 acc0[4], acc1[4];                  // [px-tile], o-tiles 0/1 for this wave
#pragma unroll
    for (int i = 0; i < 4; ++i) { acc0[i] = (f32x4)(0.f); acc1[i] = (f32x4)(0.f); }

    const char* xbase = (const char*)x + ((size_t)b << 23);   // b*128*16384*4 bytes
    int gpx  = tid & 63;                     // gather: pixel this thread fills
    int kk0  = (tid >> 6) << 3;              // gather: 8 consecutive kk
    int albase = (wid * 32 + (lane & 15)) * 32 + ((lane >> 4) << 3);   // A-frag elem offset
    // XOR-swizzled LDS elem offsets (chunk = 8 shorts = 16B)
    int welem = gpx * 40 + (((kk0 >> 3) ^ ((gpx >> 3) & 3)) << 3);     // write

    int buf = 0;
    for (int cc = 0; cc < 4; ++cc) {
        const char* xc0 = xbase + ((size_t)(cc * 32 + kk0) << 16);
#pragma unroll
        for (int kt = 0; kt < 9; ++kt) {
            int s = cc * 9 + kt;

            // ---- descriptors for (tap kt, px gpx) ----
            int so = kt * 256 + gpx;
            int   o0 = sp_off[so], o1 = sp_off[so + 64], o2 = sp_off[so + 128], o3 = sp_off[so + 192];
            float s0 = sp_w[so],   s1 = sp_w[so + 64],   s2 = sp_w[so + 128],  s3 = sp_w[so + 192];

            // ---- MLP-batched gather: issue all 32 loads, then combine ----
            float raw[32];
#pragma unroll
            for (int i = 0; i < 8; ++i) {
                const char* xp = xc0 + ((size_t)i << 16);
                raw[i * 4 + 0] = *(const float*)(xp + o0);
                raw[i * 4 + 1] = *(const float*)(xp + o1);
                raw[i * 4 + 2] = *(const float*)(xp + o2);
                raw[i * 4 + 3] = *(const float*)(xp + o3);
            }
            s16x8 hi8, lo8;
#pragma unroll
            for (int i = 0; i < 8; ++i) {
                float v = s0 * raw[i * 4 + 0];
                v = fmaf(s1, raw[i * 4 + 1], v);
                v = fmaf(s2, raw[i * 4 + 2], v);
                v = fmaf(s3, raw[i * 4 + 3], v);
                unsigned ub = __builtin_bit_cast(unsigned, v);
                unsigned short h = (unsigned short)(ub >> 16);
                float vh = __builtin_bit_cast(float, (unsigned)h << 16);
                float rr = v - vh;
                unsigned short l = (unsigned short)(__builtin_bit_cast(unsigned, rr) >> 16);
                hi8[i] = (short)h;
                lo8[i] = (short)l;
            }
            *(s16x8*)&vt_hi[buf][welem] = hi8;
            *(s16x8*)&vt_lo[buf][welem] = lo8;

            __syncthreads();   // tile ready (single barrier per slice; dbuf -> race-free)

            // ---- MFMA: D[o][px] += A[o][k] * B[k][px], 3-pass hi/lo ----
            const s16x8* pah = (const s16x8*)(wA_hi + s * 4096 + albase);
            const s16x8* pal = (const s16x8*)(wA_lo + s * 4096 + albase);
            s16x8 a_h0 = pah[0], a_h1 = pah[64];    // +16 o = 512 shorts
            s16x8 a_l0 = pal[0], a_l1 = pal[64];
#pragma unroll
            for (int pt = 0; pt < 4; ++pt) {
                int prow = pt * 16 + (lane & 15);
                int relem = prow * 40 + ((((lane >> 4)) ^ ((prow >> 3) & 3)) << 3);
                s16x8 b_h = *(const s16x8*)&vt_hi[buf][relem];
                s16x8 b_l = *(const s16x8*)&vt_lo[buf][relem];
                acc0[pt] = __builtin_amdgcn_mfma_f32_16x16x32_bf16(a_h0, b_h, acc0[pt], 0, 0, 0);
                acc0[pt] = __builtin_amdgcn_mfma_f32_16x16x32_bf16(a_h0, b_l, acc0[pt], 0, 0, 0);
                acc0[pt] = __builtin_amdgcn_mfma_f32_16x16x32_bf16(a_l0, b_h, acc0[pt], 0, 0, 0);
                acc1[pt] = __builtin_amdgcn_mfma_f32_16x16x32_bf16(a_h1, b_h, acc1[pt], 0, 0, 0);
                acc1[pt] = __builtin_amdgcn_mfma_f32_16x16x32_bf16(a_h1, b_l, acc1[pt], 0, 0, 0);
                acc1[pt] = __builtin_amdgcn_mfma_f32_16x16x32_bf16(a_l1, b_h, acc1[pt], 0, 0, 0);
            }
            buf ^= 1;
        }
    }

    // ---- write out: C/D layout col=lane&15 (px), row=(lane>>4)*4+j (o) ----
    int q = lane >> 4, pcol = lane & 15;
#pragma unroll
    for (int pt = 0; pt < 4; ++pt) {
#pragma unroll
        for (int j = 0; j < 4; ++j) {
            int o0_ = wid * 32 + q * 4 + j;
            int o1_ = o0_ + 16;
            int px  = pt * 16 + pcol;
            out[((size_t)(b * NO + o0_) << 14) + hwbase + px] = acc0[pt][j];
            out[((size_t)(b * NO + o1_) << 14) + hwbase + px] = acc1[pt][j];
        }
    }
}

extern "C" void kernel_launch(void* const* d_in, const int* in_sizes, int n_in,
                              void* d_out, int out_size, void* d_ws, size_t ws_size,
                              hipStream_t stream) {
    const float* x     = (const float*)d_in[0];
    const float* w_off = (const float*)d_in[1];
    const float* b_off = (const float*)d_in[2];
    const float* w_mod = (const float*)d_in[3];
    const float* b_mod = (const float*)d_in[4];
    const float* w_reg = (const float*)d_in[5];
    float* out = (float*)d_out;

    // ws layout: cbuf f32[4*27*16384] | wt_om f32[31104] | wA_hi s16[147456] | wA_lo s16[147456]
    float* cbuf  = (float*)d_ws;
    float* wt_om = cbuf + (size_t)NB * 27 * HWD;       // 1,769,472 floats
    short* wA_hi = (short*)(wt_om + 31104);
    short* wA_lo = wA_hi + 147456;

    hipLaunchKernelGGL(k_split_wreg,    dim3(576), dim3(256), 0, stream, w_reg, wA_hi, wA_lo);
    hipLaunchKernelGGL(k_transpose_wom, dim3(122), dim3(256), 0, stream, w_off, w_mod, wt_om);
    hipLaunchKernelGGL(k_conv_om, dim3(256), dim3(512), 0, stream, x, wt_om, cbuf);
    hipLaunchKernelGGL(k_deform, dim3(1024), dim3(256), 0, stream,
                       x, cbuf, b_off, b_mod, wA_hi, wA_lo, out);
}